// Round 4
// baseline (316.725 us; speedup 1.0000x reference)
//
#include <hip/hip_runtime.h>
#include <stdint.h>

#define F_IN 65536
#define NN 100
#define CO 60
#define G2 256              // split-K slices
#define KC (F_IN/G2)        // 256 k per slice
#define BK 64
#define NIT (KC/BK)         // 4
#define AST 72              // A LDS row stride in shorts (144 B: 16B-aligned, bank-rotating)
#define BTILE (BK*CO)       // 3840 shorts per B tile (one matrix)
#define BQ3 (3*BTILE/4)     // 2880 float4 per 3-matrix B stage
#define NB 241              // tail grid (<=256: co-resident for grid barrier)

typedef short v8s __attribute__((ext_vector_type(8)));
typedef float v4f __attribute__((ext_vector_type(4)));

__device__ __forceinline__ unsigned int f2bf(float x){
  unsigned int u = __float_as_uint(x);
  u += 0x7fffu + ((u>>16)&1u);      // round-to-nearest-even
  return u>>16;
}

__device__ __forceinline__ v4f mfma16(v8s a, v8s b, v4f c){
  return __builtin_amdgcn_mfma_f32_16x16x32_bf16(a,b,c,0,0,0);
}

// ---------------------------------------------------------------------------
// K1: split-K GEMM, 3 weight matrices per block, 512-thread blocks.
// grid = 512 blocks x 512 thr = 2 blocks/CU x 8 waves = 16 waves/CU (2x TLP
// vs round 3; traffic identical).  Wave w: m-half mh=w>>2 (mh0: mt0-3,
// mh1: mt4-6), col-tile c0=(w&3)*16.  acc[3][4] = 48 VGPR.
// Double-buffered LDS (78.3 KB, 2 blocks/CU = 156.6 <= 160), one barrier/iter.
// ---------------------------------------------------------------------------
__global__ __launch_bounds__(512,4)
void k_gemm(const float* __restrict__ x, const float* __restrict__ aw,
            const float* __restrict__ cw, float* __restrict__ dst, int partial){
  const int bid  = blockIdx.x;
  const int xcd  = bid & 7, slot = bid >> 3;   // 64 slots/XCD
  const int net  = slot & 1;
  const int s    = xcd*32 + (slot >> 1);       // k-slice
  const int k0   = s*KC;
  const int tid  = threadIdx.x;
  const int wave = tid>>6, lane = tid&63, quad = lane>>4, nl = lane&15;
  const int mh   = wave>>2;                    // m-half
  const int c0   = (wave&3)*16;
  const int ccl  = min(c0+nl, CO-1);           // clamp pad cols; masked at store

  const float* Wn = net ? cw : aw;             // [3][F_IN][CO]

  __shared__ __align__(16) unsigned short Al[2][112*AST];   // 32.25 KB
  __shared__ __align__(16) unsigned short Bl[2][3*BTILE];   // 46.08 KB

  const char* bbase0 = (const char*)(Wn + (size_t)k0*CO);

  // staging: A 4 cells (lin=p*512+tid<1792: row=lin>>4,q=lin&15),
  //          B 6 cells (lin<2880: g=lin/960, f=lin%960)
  float4 ra[4];
  float4 rbv[6];
  #pragma unroll
  for(int p=0;p<4;++p){
    int l2 = min(p*512 + tid, 1791);
    int row = l2>>4, q = l2&15;
    int rcl = min(row, NN-1);
    ra[p] = *(const float4*)(x + (size_t)rcl*F_IN + k0 + q*4);
  }
  #pragma unroll
  for(int p=0;p<6;++p){
    int li = min(p*512 + tid, BQ3-1);
    int gp = li/960, fp = li - gp*960;
    rbv[p] = *(const float4*)(bbase0 + ((size_t)gp*F_IN*CO + (size_t)fp*4)*4u);
  }

  v4f acc[3][4];
  #pragma unroll
  for(int g=0;g<3;++g)
    #pragma unroll
    for(int i=0;i<4;++i){ v4f z={0.f,0.f,0.f,0.f}; acc[g][i]=z; }

  for(int it=0; it<NIT; ++it){
    unsigned short* buf  = Al[it&1];
    unsigned short* bbuf = Bl[it&1];
    // --- write prefetched A tile (bf16) ---
    #pragma unroll
    for(int p=0;p<4;++p){
      int lin = p*512 + tid;
      if(lin < 1792){
        int row = lin>>4, q = lin&15;
        uint2 w;
        w.x = f2bf(ra[p].x) | (f2bf(ra[p].y)<<16);
        w.y = f2bf(ra[p].z) | (f2bf(ra[p].w)<<16);
        *(uint2*)(buf + row*AST + q*4) = w;
      }
    }
    // --- write prefetched B tiles (bf16, flat [3][64][60]) ---
    #pragma unroll
    for(int p=0;p<6;++p){
      int lin = p*512 + tid;
      if(lin < BQ3){
        uint2 w;
        w.x = f2bf(rbv[p].x) | (f2bf(rbv[p].y)<<16);
        w.y = f2bf(rbv[p].z) | (f2bf(rbv[p].w)<<16);
        *(uint2*)(bbuf + lin*4) = w;
      }
    }
    __syncthreads();
    // --- kick next iteration's global loads (in flight behind MFMA) ---
    if(it+1 < NIT){
      const int kb = k0 + (it+1)*BK;
      #pragma unroll
      for(int p=0;p<4;++p){
        int l2 = min(p*512 + tid, 1791);
        int row = l2>>4, q = l2&15;
        int rcl = min(row, NN-1);
        ra[p] = *(const float4*)(x + (size_t)rcl*F_IN + kb + q*4);
      }
      const char* bb2 = bbase0 + (size_t)(it+1)*BK*CO*4;
      #pragma unroll
      for(int p=0;p<6;++p){
        int li = min(p*512 + tid, BQ3-1);
        int gp = li/960, fp = li - gp*960;
        rbv[p] = *(const float4*)(bb2 + ((size_t)gp*F_IN*CO + (size_t)fp*4)*4u);
      }
    }
    // --- B fragments from LDS (3 g x 16 ds_read_u16, stride 60 shorts) ---
    v8s fB0[3], fB1[3];
    #pragma unroll
    for(int g=0;g<3;++g){
      const unsigned short* bb = bbuf + g*BTILE + quad*8*CO + ccl;
      #pragma unroll
      for(int j=0;j<8;++j){
        fB0[g][j] = (short)bb[j*CO];
        fB1[g][j] = (short)bb[32*CO + j*CO];
      }
    }
    // --- MFMA: mh0 -> mt 0..3, mh1 -> mt 4..6 (static acc indexing) ---
    if(mh==0){
      #pragma unroll
      for(int m=0;m<4;++m){
        const unsigned short* arow = buf + (m*16+nl)*AST + quad*8;
        v8s a0 = *(const v8s*)(arow);
        v8s a1 = *(const v8s*)(arow+32);
        #pragma unroll
        for(int g=0;g<3;++g){
          acc[g][m] = mfma16(a0, fB0[g], acc[g][m]);
          acc[g][m] = mfma16(a1, fB1[g], acc[g][m]);
        }
      }
    } else {
      #pragma unroll
      for(int m=0;m<3;++m){
        const unsigned short* arow = buf + ((m+4)*16+nl)*AST + quad*8;
        v8s a0 = *(const v8s*)(arow);
        v8s a1 = *(const v8s*)(arow+32);
        #pragma unroll
        for(int g=0;g<3;++g){
          acc[g][m] = mfma16(a0, fB0[g], acc[g][m]);
          acc[g][m] = mfma16(a1, fB1[g], acc[g][m]);
        }
      }
    }
  }

  // --- epilogue.  C/D layout: col=lane&15, row=quad*4+i ---
  const int c = c0 + nl;
  const int mtb = mh*4;
  const int mtn = mh ? 3 : 4;
  if(c < CO){
    #pragma unroll
    for(int g=0;g<3;++g){
      if(partial){
        float* pd = dst + ((size_t)(net*3+g)*G2 + s)*(NN*CO);
        #pragma unroll
        for(int m=0;m<4;++m){
          if(m < mtn){
            #pragma unroll
            for(int i=0;i<4;++i){
              int mm = (mtb+m)*16 + quad*4 + i;
              if(mm < NN) pd[mm*CO + c] = acc[g][m][i];
            }
          }
        }
      } else {
        float* pd = dst + (size_t)(net*3+g)*(NN*CO);
        #pragma unroll
        for(int m=0;m<4;++m){
          if(m < mtn){
            #pragma unroll
            for(int i=0;i<4;++i){
              int mm = (mtb+m)*16 + quad*4 + i;
              if(mm < NN) atomicAdd(pd + mm*CO + c, acc[g][m][i]);
            }
          }
        }
      }
    }
  }
}

// ---------------------------------------------------------------------------
// K2: fused tail — one dispatch, 241 blocks x 256 thr (co-resident on 256 CUs;
// LDS 42.9 KB -> 3 blocks/CU capacity).  Device-scope atomic grid barrier.
// Phase 1: split-K reduce P->Y (+ zero out[]).  Phase 2: cheb (blocks 0..119).
// Phase 3: final FC (blocks 0..239 logits, block 240 value+extras).
// ---------------------------------------------------------------------------
__device__ __forceinline__ void gridbar(unsigned* cnt, unsigned target){
  __syncthreads();
  if(threadIdx.x==0){
    __hip_atomic_fetch_add(cnt, 1u, __ATOMIC_ACQ_REL, __HIP_MEMORY_SCOPE_AGENT);
    while(__hip_atomic_load(cnt, __ATOMIC_ACQUIRE, __HIP_MEMORY_SCOPE_AGENT) < target){}
  }
  __syncthreads();
}

__global__ __launch_bounds__(256,1)
void k_tail(const float* __restrict__ P, float* __restrict__ Y,
            const int* __restrict__ ei, const float* __restrict__ ab,
            const float* __restrict__ cb, const float* __restrict__ afw,
            const float* __restrict__ afb, const float* __restrict__ cfw,
            const float* __restrict__ cfb, const float* __restrict__ s0,
            const float* __restrict__ s1, const float* __restrict__ s2,
            float* __restrict__ emb, float* __restrict__ out,
            unsigned* __restrict__ bar, int partial){
  const int bid = blockIdx.x;
  const int t   = threadIdx.x;       // 256

  __shared__ float L[NN][NN+1];
  __shared__ float dis[NN];
  __shared__ int   deg[NN];
  __shared__ float y0[NN], y1[NN], y2[NN], zu[NN];
  __shared__ float red[4];

  // ---- phase 1: reduce P -> Y (coalesced: lanes = consecutive r) ----
  if(partial){
    int o = bid*256 + t;
    if(o < 6*NN*CO){
      int gg = o/(NN*CO), r = o - gg*(NN*CO);
      const float* p = P + (size_t)gg*G2*(NN*CO) + r;
      float a0=0.f,a1=0.f,a2=0.f,a3=0.f;
      #pragma unroll 4
      for(int s4=0;s4<G2;s4+=4){
        a0 += p[(size_t)(s4  )*(NN*CO)];
        a1 += p[(size_t)(s4+1)*(NN*CO)];
        a2 += p[(size_t)(s4+2)*(NN*CO)];
        a3 += p[(size_t)(s4+3)*(NN*CO)];
      }
      Y[o] = (a0+a1)+(a2+a3);
    }
  }
  if(bid==130 && t<101) out[t] = 0.f;

  gridbar(bar, NB);

  // ---- phase 2: cheb combine + tanh (blocks 0..119) ----
  if(bid < 120){
    const int net = bid / CO;
    const int c   = bid % CO;
    for(int i=t;i<NN*(NN+1);i+=256) ((float*)L)[i]=0.f;
    if(t<NN) deg[t]=0;
    __syncthreads();
    for(int e=t;e<2000;e+=256) atomicAdd(&deg[ei[e]],1);
    __syncthreads();
    if(t<NN) dis[t] = deg[t]>0 ? rsqrtf((float)deg[t]) : 0.f;
    __syncthreads();
    for(int e=t;e<2000;e+=256){
      int ss = ei[e], d = ei[2000+e];
      atomicAdd(&L[d][ss], -dis[ss]*dis[d]);
    }
    if(t<NN){
      const float* yb = Y + (size_t)net*3*NN*CO + t*CO + c;
      y0[t]=yb[0]; y1[t]=yb[NN*CO]; y2[t]=yb[2*NN*CO];
    }
    __syncthreads();
    if(t<NN){
      float sv=0.f;
      #pragma unroll 4
      for(int j=0;j<NN;++j) sv += L[t][j]*y2[j];
      zu[t] = y1[t] + 2.f*sv;
    }
    __syncthreads();
    if(t<NN){
      float sv=0.f;
      #pragma unroll 4
      for(int j=0;j<NN;++j) sv += L[t][j]*zu[j];
      float b = (net==0) ? ab[c] : cb[c];
      emb[net*NN*CO + t*CO + c] = tanhf(y0[t] - y2[t] + sv + b);
    }
  }

  gridbar(bar, 2*NB);

  // ---- phase 3: final FC ----
  if(bid < 240){
    // logits partials: block covers 25 emb rows; lanes = output cols (coalesced)
    if(t < 100){
      const float* e = emb + bid*25;
      const float* w = afw + (size_t)bid*25*100 + t;
      float p = 0.f;
      #pragma unroll
      for(int i=0;i<25;++i) p += e[i]*w[(size_t)i*100];
      atomicAdd(&out[t], p);
    }
  } else {
    // value dot + biases + scalar extras
    float p = 0.f;
    const float* e = emb + 6000;
    for(int i=t;i<6000;i+=256) p += e[i]*cfw[i];
    #pragma unroll
    for(int o=32;o>0;o>>=1) p += __shfl_down(p,o,64);
    if((t&63)==0) red[t>>6]=p;
    __syncthreads();
    if(t==0){
      float tot = red[0]+red[1]+red[2]+red[3];
      out[100] = tot + s0[0]*cfw[6000] + s1[0]*cfw[6001] + s2[0]*cfw[6002] + cfb[0];
    }
    if(t<100){
      atomicAdd(&out[t], afb[t] + s0[0]*afw[600000+t] + s1[0]*afw[600100+t] + s2[0]*afw[600200+t]);
    }
  }
}

extern "C" void kernel_launch(void* const* d_in, const int* in_sizes, int n_in,
                              void* d_out, int out_size, void* d_ws, size_t ws_size,
                              hipStream_t stream){
  const float* x   = (const float*)d_in[0];
  const int*   ei  = (const int*)d_in[1];
  const float* s0  = (const float*)d_in[2];
  const float* s1  = (const float*)d_in[3];
  const float* s2  = (const float*)d_in[4];
  const float* aw  = (const float*)d_in[5];
  const float* ab  = (const float*)d_in[6];
  const float* cw  = (const float*)d_in[7];
  const float* cb  = (const float*)d_in[8];
  const float* afw = (const float*)d_in[9];
  const float* afb = (const float*)d_in[10];
  const float* cfw = (const float*)d_in[11];
  const float* cfb = (const float*)d_in[12];
  float* out = (float*)d_out;

  float*    Y   = (float*)d_ws;                  // [6][6000]
  float*    emb = Y + 6*NN*CO;                   // [2][6000]
  unsigned* bar = (unsigned*)(emb + 2*NN*CO);    // [16] barrier counter (64 B)
  float*    P   = (float*)(bar + 16);            // [6][G2][6000] split-K partials
  const size_t need = (size_t)(6*NN*CO + 2*NN*CO + 16)*4 + (size_t)6*G2*NN*CO*4;
  const int partial = (ws_size >= need) ? 1 : 0;

  hipMemsetAsync(bar, 0, 8, stream);
  if(!partial) hipMemsetAsync(Y, 0, 6*NN*CO*sizeof(float), stream);

  k_gemm<<<dim3(512), 512, 0, stream>>>(x, aw, cw, partial ? P : Y, partial);
  k_tail<<<dim3(NB), 256, 0, stream>>>(P, Y, ei, ab, cb, afw, afb, cfw, cfb,
                                       s0, s1, s2, emb, out, bar, partial);
}